// Round 10
// baseline (421.038 us; speedup 1.0000x reference)
//
#include <hip/hip_runtime.h>

#define HID 128
#define TWO_HID 256
#define NEMB (HID*HID)
#define NWS  (4*HID*TWO_HID)

typedef __attribute__((ext_vector_type(8))) short short8;
typedef __attribute__((ext_vector_type(4))) float f32x4;

__device__ inline unsigned short f2b(float f){
  unsigned u = __float_as_uint(f);
  unsigned r = u + 0x7FFFu + ((u >> 16) & 1u);   // RNE
  return (unsigned short)(r >> 16);
}
__device__ inline unsigned pack2(float lo, float hi){
  return (unsigned)f2b(lo) | ((unsigned)f2b(hi) << 16);
}
__device__ inline float blo(unsigned u){ return __uint_as_float(u << 16); }
__device__ inline float bhi(unsigned u){ return __uint_as_float(u & 0xFFFF0000u); }

// ---------- prep: weight cvt + degree count (merged; NEMB+NWS < E) ----------
__global__ void k_prep(const int* __restrict__ dst, int* __restrict__ deg, int E,
                       const float* __restrict__ Wemb, const float* __restrict__ Ws,
                       unsigned short* __restrict__ Wembb, unsigned short* __restrict__ Wsb){
  int i = blockIdx.x*blockDim.x + threadIdx.x;
  if (i < NEMB) Wembb[i] = f2b(Wemb[i]);
  else if (i < NEMB + NWS) Wsb[i - NEMB] = f2b(Ws[i - NEMB]);
  if (i < E) atomicAdd(&deg[dst[i]], 1);
}

__global__ __launch_bounds__(256) void k_scan1(const int* __restrict__ deg, int* __restrict__ loc,
                                               int* __restrict__ bsum, int N){
  const int tid = threadIdx.x;
  const int i = blockIdx.x*256 + tid;
  const int lane = tid & 63, wv = tid >> 6;
  int v = (i < N) ? deg[i] : 0;
  int s = v;
  #pragma unroll
  for (int m=1; m<64; m<<=1){
    int t = __shfl_up(s, m, 64);
    if (lane >= m) s += t;
  }
  __shared__ int wsum[4];
  if (lane == 63) wsum[wv] = s;
  __syncthreads();
  if (tid == 0){
    int a = 0;
    #pragma unroll
    for (int q=0;q<4;q++){ int t = wsum[q]; wsum[q] = a; a += t; }
    bsum[blockIdx.x] = a;
  }
  __syncthreads();
  if (i < N) loc[i] = s - v + wsum[wv];
}

__global__ __launch_bounds__(256) void k_scan2(int* __restrict__ bsum, int nb){
  const int tid = threadIdx.x;
  const int lane = tid & 63, wv = tid >> 6;
  int v = (tid < nb) ? bsum[tid] : 0;
  int s = v;
  #pragma unroll
  for (int m=1; m<64; m<<=1){
    int t = __shfl_up(s, m, 64);
    if (lane >= m) s += t;
  }
  __shared__ int wsum[4];
  if (lane == 63) wsum[wv] = s;
  __syncthreads();
  if (tid == 0){
    int a = 0;
    #pragma unroll
    for (int q=0;q<4;q++){ int t = wsum[q]; wsum[q] = a; a += t; }
  }
  __syncthreads();
  if (tid < nb) bsum[tid] = s - v + wsum[wv];
}

__global__ __launch_bounds__(256) void k_scan3(const int* __restrict__ deg, const int* __restrict__ loc,
                                               const int* __restrict__ bsum, int* __restrict__ offs,
                                               float* __restrict__ invd, int N, int E){
  const int i = blockIdx.x*256 + threadIdx.x;
  if (i < N){
    offs[i] = loc[i] + bsum[blockIdx.x];
    int d = deg[i];
    invd[i] = (d > 0) ? 1.0f / (float)d : -1.0f;   // deg0 sentinel
  }
  if (i == 0) offs[N] = E;
}

__global__ void k_fill(const int* __restrict__ src, const int* __restrict__ dst,
                       const int* __restrict__ offs, int* __restrict__ cursor,
                       int* __restrict__ ssrc, int E){
  int e = blockIdx.x*blockDim.x + threadIdx.x;
  if (e < E){
    int d = dst[e];
    int pos = offs[d] + atomicAdd(&cursor[d], 1);
    ssrc[pos] = src[e];
  }
}

// ---------- input embedding (MFMA bf16) ----------
__global__ __launch_bounds__(256) void k_embed(const float* __restrict__ h0, const unsigned short* __restrict__ Wb,
                                               const float* __restrict__ b, float* __restrict__ h,
                                               unsigned short* __restrict__ xh, int Ntiles){
  const int tid = threadIdx.x;
  const int w = tid >> 6, l = tid & 63;
  const int l15 = l & 15, lhi = l >> 4;
  const int cb = w * 32;
  short8 bf[2][4];
  #pragma unroll
  for (int t=0;t<2;t++){
    #pragma unroll
    for (int s=0;s<4;s++)
      bf[t][s] = *(const short8*)(Wb + (size_t)(cb + t*16 + l15)*HID + s*32 + lhi*8);
  }
  const float bias0 = b[cb + l15];
  const float bias1 = b[cb + 16 + l15];
  for (int tile = blockIdx.x; tile < Ntiles; tile += gridDim.x){
    const int row0 = tile * 16;
    f32x4 acc0 = {0.f,0.f,0.f,0.f}, acc1 = {0.f,0.f,0.f,0.f};
    #pragma unroll
    for (int s=0;s<4;s++){
      const float* ap = h0 + (size_t)(row0 + l15)*HID + s*32 + lhi*8;
      float4 x0 = *(const float4*)ap;
      float4 x1 = *(const float4*)(ap + 4);
      short8 f;
      f[0]=(short)f2b(x0.x); f[1]=(short)f2b(x0.y); f[2]=(short)f2b(x0.z); f[3]=(short)f2b(x0.w);
      f[4]=(short)f2b(x1.x); f[5]=(short)f2b(x1.y); f[6]=(short)f2b(x1.z); f[7]=(short)f2b(x1.w);
      acc0 = __builtin_amdgcn_mfma_f32_16x16x32_bf16(f, bf[0][s], acc0, 0,0,0);
      acc1 = __builtin_amdgcn_mfma_f32_16x16x32_bf16(f, bf[1][s], acc1, 0,0,0);
    }
    #pragma unroll
    for (int r=0;r<4;r++){
      const int row = row0 + lhi*4 + r;
      float v0 = acc0[r] + bias0;
      float v1 = acc1[r] + bias1;
      h[(size_t)row*HID + cb + l15]      = v0;
      h[(size_t)row*HID + cb + 16 + l15] = v1;
      xh[(size_t)row*HID + cb + l15]      = f2b(v0);
      xh[(size_t)row*HID + cb + 16 + l15] = f2b(v1);
    }
  }
}

// ---------- layer-1 aggregation: cbt[v] = mean of xh[nbrs]  (uint4 gather: 4 rows/instr) ----------
__global__ __launch_bounds__(256) void k_agg(const uint4* __restrict__ xh4, const int* __restrict__ offs,
                                             const int* __restrict__ ssrc, const float* __restrict__ invd,
                                             uint4* __restrict__ cb4, int N){
  int gid = blockIdx.x*blockDim.x + threadIdx.x;
  int node = gid >> 6;
  int l = gid & 63;
  if (node >= N) return;
  const int j = l & 15, g = l >> 4;
  int e0 = offs[node], e1 = offs[node+1];
  float a0=0,a1=0,a2=0,a3=0,a4=0,a5=0,a6=0,a7=0;
  int e = e0;
  for (; e + 7 < e1; e += 8){
    int s0 = ssrc[e+g], s1 = ssrc[e+g+4];
    uint4 v0 = xh4[(size_t)s0*16 + j];
    uint4 v1 = xh4[(size_t)s1*16 + j];
    a0 += blo(v0.x)+blo(v1.x); a1 += bhi(v0.x)+bhi(v1.x);
    a2 += blo(v0.y)+blo(v1.y); a3 += bhi(v0.y)+bhi(v1.y);
    a4 += blo(v0.z)+blo(v1.z); a5 += bhi(v0.z)+bhi(v1.z);
    a6 += blo(v0.w)+blo(v1.w); a7 += bhi(v0.w)+bhi(v1.w);
  }
  for (; e < e1; e += 4){
    int eg = e + g;
    if (eg < e1){
      int s = ssrc[eg];
      uint4 v = xh4[(size_t)s*16 + j];
      a0 += blo(v.x); a1 += bhi(v.x);
      a2 += blo(v.y); a3 += bhi(v.y);
      a4 += blo(v.z); a5 += bhi(v.z);
      a6 += blo(v.w); a7 += bhi(v.w);
    }
  }
  a0 += __shfl_xor(a0,16,64); a0 += __shfl_xor(a0,32,64);
  a1 += __shfl_xor(a1,16,64); a1 += __shfl_xor(a1,32,64);
  a2 += __shfl_xor(a2,16,64); a2 += __shfl_xor(a2,32,64);
  a3 += __shfl_xor(a3,16,64); a3 += __shfl_xor(a3,32,64);
  a4 += __shfl_xor(a4,16,64); a4 += __shfl_xor(a4,32,64);
  a5 += __shfl_xor(a5,16,64); a5 += __shfl_xor(a5,32,64);
  a6 += __shfl_xor(a6,16,64); a6 += __shfl_xor(a6,32,64);
  a7 += __shfl_xor(a7,16,64); a7 += __shfl_xor(a7,32,64);
  float id = invd[node];
  float sc = fabsf(id) * ((id > 0.f) ? 1.f : 0.f);
  if (g == 0){
    uint4 o;
    o.x = pack2(a0*sc, a1*sc);
    o.y = pack2(a2*sc, a3*sc);
    o.z = pack2(a4*sc, a5*sc);
    o.w = pack2(a6*sc, a7*sc);
    cb4[(size_t)node*16 + j] = o;
  }
}

// ---------- layer GEMM (MFMA bf16) + L2norm + relu + BN partials; z stored bf16 ----------
__global__ __launch_bounds__(256) void k_gemm(const unsigned short* __restrict__ xh,
                                              const unsigned short* __restrict__ cbt,
                                              const unsigned short* __restrict__ Wb, const float* __restrict__ b,
                                              unsigned short* __restrict__ zb16, float* __restrict__ colsums, int Ntiles){
  __shared__ float rowss[2][16][4];
  const int tid = threadIdx.x;
  const int w = tid >> 6, l = tid & 63;
  const int l15 = l & 15, lhi = l >> 4;
  const int cb = w * 32;
  short8 bf[2][8];
  #pragma unroll
  for (int t=0;t<2;t++){
    #pragma unroll
    for (int s=0;s<8;s++)
      bf[t][s] = *(const short8*)(Wb + (size_t)(cb + t*16 + l15)*TWO_HID + s*32 + lhi*8);
  }
  const float bias0 = b[cb + l15];
  const float bias1 = b[cb + 16 + l15];
  float s1a = 0.f, s2a = 0.f, s1b = 0.f, s2b = 0.f;
  int pp = 0;
  for (int tile = blockIdx.x; tile < Ntiles; tile += gridDim.x, pp ^= 1){
    const int row0 = tile * 16;
    f32x4 acc0 = {0.f,0.f,0.f,0.f}, acc1 = {0.f,0.f,0.f,0.f};
    #pragma unroll
    for (int s=0;s<4;s++){
      short8 a = *(const short8*)(xh + (size_t)(row0 + l15)*HID + s*32 + lhi*8);
      acc0 = __builtin_amdgcn_mfma_f32_16x16x32_bf16(a, bf[0][s], acc0, 0,0,0);
      acc1 = __builtin_amdgcn_mfma_f32_16x16x32_bf16(a, bf[1][s], acc1, 0,0,0);
    }
    #pragma unroll
    for (int s=0;s<4;s++){
      short8 a = *(const short8*)(cbt + (size_t)(row0 + l15)*HID + s*32 + lhi*8);
      acc0 = __builtin_amdgcn_mfma_f32_16x16x32_bf16(a, bf[0][4+s], acc0, 0,0,0);
      acc1 = __builtin_amdgcn_mfma_f32_16x16x32_bf16(a, bf[1][4+s], acc1, 0,0,0);
    }
    float v0[4], v1[4], pr[4];
    #pragma unroll
    for (int r=0;r<4;r++){
      v0[r] = acc0[r] + bias0;
      v1[r] = acc1[r] + bias1;
      pr[r] = v0[r]*v0[r] + v1[r]*v1[r];
    }
    #pragma unroll
    for (int m=1;m<=8;m<<=1){
      #pragma unroll
      for (int r=0;r<4;r++) pr[r] += __shfl_xor(pr[r], m, 64);
    }
    if (l15 == 0){
      #pragma unroll
      for (int r=0;r<4;r++) rowss[pp][lhi*4+r][w] = pr[r];
    }
    __syncthreads();
    #pragma unroll
    for (int r=0;r<4;r++){
      const int i = lhi*4 + r;
      f32x4 q = *(const f32x4*)&rowss[pp][i][0];
      float ss = (q[0]+q[1]) + (q[2]+q[3]);
      float sc = 1.f / fmaxf(sqrtf(ss), 1e-12f);
      float z0 = fmaxf(v0[r]*sc, 0.f);
      float z1 = fmaxf(v1[r]*sc, 0.f);
      zb16[(size_t)(row0+i)*HID + cb + l15]      = f2b(z0);
      zb16[(size_t)(row0+i)*HID + cb + 16 + l15] = f2b(z1);
      s1a += z0; s2a += z0*z0;
      s1b += z1; s2b += z1*z1;
    }
  }
  s1a += __shfl_xor(s1a,16,64); s1a += __shfl_xor(s1a,32,64);
  s2a += __shfl_xor(s2a,16,64); s2a += __shfl_xor(s2a,32,64);
  s1b += __shfl_xor(s1b,16,64); s1b += __shfl_xor(s1b,32,64);
  s2b += __shfl_xor(s2b,16,64); s2b += __shfl_xor(s2b,32,64);
  if (lhi == 0){
    atomicAdd(&colsums[cb + l15],            s1a);
    atomicAdd(&colsums[128 + cb + l15],      s2a);
    atomicAdd(&colsums[cb + 16 + l15],       s1b);
    atomicAdd(&colsums[128 + cb + 16 + l15], s2b);
  }
}

// ====== fused BN-apply(prev layer) + incremental aggregation (uint4 gather) ======
__global__ __launch_bounds__(256) void k_aggbn(const unsigned* __restrict__ zbu,
                                               const float* __restrict__ cs,
                                               const float* __restrict__ gamma, const float* __restrict__ beta,
                                               float* __restrict__ h, unsigned* __restrict__ xhu,
                                               uint4* __restrict__ cb4,
                                               const int* __restrict__ offs, const int* __restrict__ ssrc,
                                               const float* __restrict__ invd, int N, float invN){
  int gid = blockIdx.x*blockDim.x + threadIdx.x;
  int node = gid >> 6;
  int l = gid & 63;
  if (node >= N) return;
  const int j = l & 15, g = l >> 4;

  // ---- BN apply + residual for own node (64-lane float2 layout) ----
  {
    float2 s1 = ((const float2*)cs)[l];
    float2 s2 = ((const float2*)(cs + 128))[l];
    float2 gm = ((const float2*)gamma)[l];
    float2 bt = ((const float2*)beta)[l];
    float mux = s1.x*invN,           muy = s1.y*invN;
    float vax = s2.x*invN - mux*mux, vay = s2.y*invN - muy*muy;
    float scx = gm.x * rsqrtf(vax + 1e-5f), scy = gm.y * rsqrtf(vay + 1e-5f);
    float shx = bt.x - mux*scx,             shy = bt.y - muy*scy;
    size_t idx = (size_t)node*64 + l;
    unsigned zu = zbu[idx];
    float2 hv = ((const float2*)h)[idx];
    float nx = fmaf(blo(zu), scx, hv.x + shx);
    float ny = fmaf(bhi(zu), scy, hv.y + shy);
    ((float2*)h)[idx] = make_float2(nx, ny);
    xhu[idx] = pack2(nx, ny);
  }

  // ---- gather neighbors' z (uint4: 4 rows per instruction) ----
  const uint4* zb4 = (const uint4*)zbu;
  int e0 = offs[node], e1 = offs[node+1];
  float a0=0,a1=0,a2=0,a3=0,a4=0,a5=0,a6=0,a7=0;
  int e = e0;
  for (; e + 7 < e1; e += 8){
    int s0 = ssrc[e+g], s1_ = ssrc[e+g+4];
    uint4 v0 = zb4[(size_t)s0*16 + j];
    uint4 v1 = zb4[(size_t)s1_*16 + j];
    a0 += blo(v0.x)+blo(v1.x); a1 += bhi(v0.x)+bhi(v1.x);
    a2 += blo(v0.y)+blo(v1.y); a3 += bhi(v0.y)+bhi(v1.y);
    a4 += blo(v0.z)+blo(v1.z); a5 += bhi(v0.z)+bhi(v1.z);
    a6 += blo(v0.w)+blo(v1.w); a7 += bhi(v0.w)+bhi(v1.w);
  }
  for (; e < e1; e += 4){
    int eg = e + g;
    if (eg < e1){
      int s = ssrc[eg];
      uint4 v = zb4[(size_t)s*16 + j];
      a0 += blo(v.x); a1 += bhi(v.x);
      a2 += blo(v.y); a3 += bhi(v.y);
      a4 += blo(v.z); a5 += bhi(v.z);
      a6 += blo(v.w); a7 += bhi(v.w);
    }
  }
  a0 += __shfl_xor(a0,16,64); a0 += __shfl_xor(a0,32,64);
  a1 += __shfl_xor(a1,16,64); a1 += __shfl_xor(a1,32,64);
  a2 += __shfl_xor(a2,16,64); a2 += __shfl_xor(a2,32,64);
  a3 += __shfl_xor(a3,16,64); a3 += __shfl_xor(a3,32,64);
  a4 += __shfl_xor(a4,16,64); a4 += __shfl_xor(a4,32,64);
  a5 += __shfl_xor(a5,16,64); a5 += __shfl_xor(a5,32,64);
  a6 += __shfl_xor(a6,16,64); a6 += __shfl_xor(a6,32,64);
  a7 += __shfl_xor(a7,16,64); a7 += __shfl_xor(a7,32,64);

  // ---- c += (mean(z)*sc + sh)*[deg>0] for features 8j..8j+7 ----
  float idv = invd[node];
  float ida = fabsf(idv);
  float m = (idv > 0.f) ? 1.f : 0.f;
  float4 p1a = ((const float4*)cs)[2*j],       p1b = ((const float4*)cs)[2*j+1];
  float4 p2a = ((const float4*)(cs+128))[2*j], p2b = ((const float4*)(cs+128))[2*j+1];
  float4 gA  = ((const float4*)gamma)[2*j],    gB  = ((const float4*)gamma)[2*j+1];
  float4 bA  = ((const float4*)beta)[2*j],     bB  = ((const float4*)beta)[2*j+1];
  float mu0=p1a.x*invN, mu1=p1a.y*invN, mu2=p1a.z*invN, mu3=p1a.w*invN;
  float mu4=p1b.x*invN, mu5=p1b.y*invN, mu6=p1b.z*invN, mu7=p1b.w*invN;
  float sc0=gA.x*rsqrtf(p2a.x*invN-mu0*mu0+1e-5f), sc1=gA.y*rsqrtf(p2a.y*invN-mu1*mu1+1e-5f);
  float sc2=gA.z*rsqrtf(p2a.z*invN-mu2*mu2+1e-5f), sc3=gA.w*rsqrtf(p2a.w*invN-mu3*mu3+1e-5f);
  float sc4=gB.x*rsqrtf(p2b.x*invN-mu4*mu4+1e-5f), sc5=gB.y*rsqrtf(p2b.y*invN-mu5*mu5+1e-5f);
  float sc6=gB.z*rsqrtf(p2b.z*invN-mu6*mu6+1e-5f), sc7=gB.w*rsqrtf(p2b.w*invN-mu7*mu7+1e-5f);
  float sh0=bA.x-mu0*sc0, sh1=bA.y-mu1*sc1, sh2=bA.z-mu2*sc2, sh3=bA.w-mu3*sc3;
  float sh4=bB.x-mu4*sc4, sh5=bB.y-mu5*sc5, sh6=bB.z-mu6*sc6, sh7=bB.w-mu7*sc7;
  if (g == 0){
    size_t ci = (size_t)node*16 + j;
    uint4 cu = cb4[ci];
    uint4 o;
    o.x = pack2(blo(cu.x) + fmaf(a0*ida, sc0, sh0)*m, bhi(cu.x) + fmaf(a1*ida, sc1, sh1)*m);
    o.y = pack2(blo(cu.y) + fmaf(a2*ida, sc2, sh2)*m, bhi(cu.y) + fmaf(a3*ida, sc3, sh3)*m);
    o.z = pack2(blo(cu.z) + fmaf(a4*ida, sc4, sh4)*m, bhi(cu.z) + fmaf(a5*ida, sc5, sh5)*m);
    o.w = pack2(blo(cu.w) + fmaf(a6*ida, sc6, sh6)*m, bhi(cu.w) + fmaf(a7*ida, sc7, sh7)*m);
    cb4[ci] = o;
  }
}

// ---------- final BN apply (layer 4) ----------
__global__ __launch_bounds__(256) void k_bnfinal(const unsigned* __restrict__ zbu,
                                                 const float* __restrict__ colsums,
                                                 const float* __restrict__ gamma, const float* __restrict__ beta,
                                                 float* __restrict__ h, int Nh, float invN){
  int i = blockIdx.x*blockDim.x + threadIdx.x;
  if (i >= Nh) return;
  int j = i & 63;
  float2 s1 = ((const float2*)colsums)[j];
  float2 s2 = ((const float2*)(colsums + 128))[j];
  float2 g  = ((const float2*)gamma)[j];
  float2 bt = ((const float2*)beta)[j];
  float mux = s1.x*invN,           muy = s1.y*invN;
  float vax = s2.x*invN - mux*mux, vay = s2.y*invN - muy*muy;
  float scx = g.x * rsqrtf(vax + 1e-5f), scy = g.y * rsqrtf(vay + 1e-5f);
  float shx = bt.x - mux*scx,            shy = bt.y - muy*scy;
  unsigned zu = zbu[i];
  float2 hv = ((const float2*)h)[i];
  float nx = fmaf(blo(zu), scx, hv.x + shx);
  float ny = fmaf(bhi(zu), scy, hv.y + shy);
  ((float2*)h)[i] = make_float2(nx, ny);
}

extern "C" void kernel_launch(void* const* d_in, const int* in_sizes, int n_in,
                              void* d_out, int out_size, void* d_ws, size_t ws_size,
                              hipStream_t stream){
  const float* h0   = (const float*)d_in[0];
  const int*   src  = (const int*)d_in[1];
  const int*   dst  = (const int*)d_in[2];
  const float* Wemb = (const float*)d_in[3];
  const float* bemb = (const float*)d_in[4];
  const float* Ws   = (const float*)d_in[5];
  const float* bs   = (const float*)d_in[6];
  const float* gam  = (const float*)d_in[7];
  const float* bet  = (const float*)d_in[8];
  const int N = in_sizes[0] / HID;
  const int E = in_sizes[1];
  const int Ntiles = N / 16;
  const int NB = (N + 255) / 256;
  float* h = (float*)d_out;

  char* ws = (char*)d_ws;
  size_t off = 0;
  auto alloc = [&](size_t bytes)->char*{
    char* p = ws + off;
    off = (off + bytes + 255) & ~(size_t)255;
    return p;
  };
  int*   deg      = (int*)  alloc((size_t)N*4);        // deg,cursor,colsums contiguous -> one memset
  int*   cursor   = (int*)  alloc((size_t)N*4);
  float* colsums  = (float*)alloc(4*256*4);
  int*   offs     = (int*)  alloc((size_t)(N+1)*4);
  int*   loc      = (int*)  alloc((size_t)N*4);
  int*   bsum     = (int*)  alloc((size_t)NB*4);
  float* invd     = (float*)alloc((size_t)N*4);
  int*   ssrc     = (int*)  alloc((size_t)E*4);
  unsigned short* Wembb = (unsigned short*)alloc((size_t)NEMB*2);
  unsigned short* Wsb   = (unsigned short*)alloc((size_t)NWS*2);
  unsigned short* xh    = (unsigned short*)alloc((size_t)N*HID*2);   // bf16 h mirror
  unsigned short* cbt   = (unsigned short*)alloc((size_t)N*HID*2);   // bf16 aggregate (incremental)
  unsigned short* zb16  = (unsigned short*)alloc((size_t)N*HID*2);   // bf16 z

  hipMemsetAsync(deg, 0, (size_t)2*N*4 + 4*256*4, stream);

  hipLaunchKernelGGL(k_prep,  dim3((E+255)/256),   dim3(256), 0, stream,
                     dst, deg, E, Wemb, Ws, Wembb, Wsb);
  hipLaunchKernelGGL(k_scan1, dim3(NB),  dim3(256), 0, stream, deg, loc, bsum, N);
  hipLaunchKernelGGL(k_scan2, dim3(1),   dim3(256), 0, stream, bsum, NB);
  hipLaunchKernelGGL(k_scan3, dim3(NB),  dim3(256), 0, stream, deg, loc, bsum, offs, invd, N, E);
  hipLaunchKernelGGL(k_fill,  dim3((E+255)/256),   dim3(256), 0, stream, src, dst, offs, cursor, ssrc, E);

  hipLaunchKernelGGL(k_embed, dim3(512), dim3(256), 0, stream, h0, Wembb, bemb, h, xh, Ntiles);

  const float invN = 1.0f / (float)N;
  const int aggGrid = (N*64 + 255) / 256;

  // layer 1
  hipLaunchKernelGGL(k_agg, dim3(aggGrid), dim3(256), 0, stream,
                     (const uint4*)xh, offs, ssrc, invd, (uint4*)cbt, N);
  hipLaunchKernelGGL(k_gemm, dim3(512), dim3(256), 0, stream,
                     xh, cbt, Wsb, bs, zb16, colsums, Ntiles);
  // layers 2..4
  for (int l=1;l<4;l++){
    hipLaunchKernelGGL(k_aggbn, dim3(aggGrid), dim3(256), 0, stream,
                       (const unsigned*)zb16, colsums + (size_t)(l-1)*256,
                       gam + (size_t)(l-1)*HID, bet + (size_t)(l-1)*HID,
                       h, (unsigned*)xh, (uint4*)cbt, offs, ssrc, invd, N, invN);
    hipLaunchKernelGGL(k_gemm, dim3(512), dim3(256), 0, stream,
                       xh, cbt, Wsb + (size_t)l*HID*TWO_HID, bs + (size_t)l*HID,
                       zb16, colsums + (size_t)l*256, Ntiles);
  }
  // final BN (layer 4)
  hipLaunchKernelGGL(k_bnfinal, dim3(aggGrid), dim3(256), 0, stream,
                     (const unsigned*)zb16, colsums + (size_t)3*256,
                     gam + (size_t)3*HID, bet + (size_t)3*HID, h, N*64, invN);
}